// Round 13
// baseline (324.023 us; speedup 1.0000x reference)
//
#include <hip/hip_runtime.h>
#include <hip/hip_fp16.h>
#include <math.h>

// 2-layer GNN (linear -> gather -> scatter-mean -> relu) x2, segment-max
// pool over 64 graphs, FC head, log_softmax. N=100k, E=1.6M, D=H=128, G=64.
//
// R17 -> R18: R17's safe-fusion recipe (wave-independent 16-node spans,
// register state, sparse flush) WORKED (aggp2 51.4us, total 284). Apply it
// to the agg1->B->gemm2 round-trip: k_agf = per-wave {gather-mean 16 nodes
// into a WAVE-PRIVATE LDS slice, one 4-wave barrier, wave-level 16x128
// W2-MFMA -> A2 fp8}. B (25.6MB write + 25.6MB read) and the gemm2 launch
// disappear. Differs from R13's failed fusion: 4-wave blocks @17.4KB LDS
// -> 8 blocks/CU = 32 waves/CU (max occupancy; R13 had 38% at 8-wave
// blocks), straggler coupling 4 waves not 8. Launches 7+memset->6+memset.
// agg-floor form everywhere (42.9us verified); aggp2/fc unchanged.

#define BUCKET_SHIFT 8
#define BUCKET_SIZE 256
#define MAXBUCK 512     // >= nbuck = ceil(N/256) = 391
#define BIN_CHUNK 4096
#define CAP 4608        // bucket window capacity; mean 4092 -> +8 sigma
#define LSTR 136        // LDS row stride in halves (272B): %8==0 for b128

typedef _Float16 half8 __attribute__((ext_vector_type(8)));
typedef _Float16 half4v __attribute__((ext_vector_type(4)));
typedef _Float16 half2v __attribute__((ext_vector_type(2)));
typedef float floatx4 __attribute__((ext_vector_type(4)));
typedef float floatx2 __attribute__((ext_vector_type(2)));

#define RFL(v) __builtin_amdgcn_readfirstlane(v)

// ---------------- multisplit binning + bounds + W-convert -------------------
// pack: low 24 bits = src (N < 2^24), high 8 bits = dst & 255
// bcur starts 0 (memset); window base i*CAP added locally.
__global__ __launch_bounds__(256) void k_bin(
        const int* __restrict__ src, const int* __restrict__ dst,
        int* __restrict__ bcur, int* __restrict__ staging,
        const int* __restrict__ batch, int* __restrict__ gstart,
        int* __restrict__ gend,
        const float* __restrict__ W1, const float* __restrict__ W2,
        _Float16* __restrict__ w1h, _Float16* __restrict__ w2h,
        int E, int N, int nbuck) {
    __shared__ int lh[MAXBUCK];
    __shared__ int lbase[MAXBUCK];
    __shared__ int lc[MAXBUCK];
    int t = threadIdx.x;
    for (int i = t; i < nbuck; i += 256) { lh[i] = 0; lc[i] = 0; }

    // folded W -> fp16 convert: blocks 0..63 x 256 threads = 16384 = 128*128
    if (blockIdx.x < 64) {
        int i = blockIdx.x * 256 + t;
        w1h[i] = (_Float16)W1[i];
        w2h[i] = (_Float16)W2[i];
    }

    // fused k_bounds: 391 blocks x 256 threads >= N
    int n = blockIdx.x * 256 + t;
    if (n < N) {
        int b = batch[n];
        if (n == 0 || batch[n - 1] != b) gstart[b] = n;
        if (n == N - 1 || batch[n + 1] != b) gend[b] = n + 1;
    }
    __syncthreads();

    int base = blockIdx.x * BIN_CHUNK;
    if (base + BIN_CHUNK <= E) {
        // full chunk: 16 edges/thread in registers, int4 coalesced loads
        int ds[16], ss[16];
        const int4* dv = (const int4*)(dst + base);
        const int4* sv = (const int4*)(src + base);
        #pragma unroll
        for (int j = 0; j < 4; ++j) {
            int4 d = dv[j * 256 + t];
            int4 s = sv[j * 256 + t];
            ds[j * 4 + 0] = d.x; ds[j * 4 + 1] = d.y;
            ds[j * 4 + 2] = d.z; ds[j * 4 + 3] = d.w;
            ss[j * 4 + 0] = s.x; ss[j * 4 + 1] = s.y;
            ss[j * 4 + 2] = s.z; ss[j * 4 + 3] = s.w;
        }
        #pragma unroll
        for (int q = 0; q < 16; ++q)
            atomicAdd(&lh[ds[q] >> BUCKET_SHIFT], 1);
        __syncthreads();
        for (int i = t; i < nbuck; i += 256)
            if (lh[i]) lbase[i] = i * CAP + atomicAdd(&bcur[i], lh[i]);
        __syncthreads();
        #pragma unroll
        for (int q = 0; q < 16; ++q) {
            int d = ds[q];
            int b = d >> BUCKET_SHIFT;
            int pos = lbase[b] + atomicAdd(&lc[b], 1);
            if (pos < (b + 1) * CAP)   // overflow guard
                staging[pos] = ss[q] | ((d & (BUCKET_SIZE - 1)) << 24);
        }
    } else {
        // tail chunk (last block only): scalar path
        for (int e = base + t; e < E; e += 256)
            atomicAdd(&lh[dst[e] >> BUCKET_SHIFT], 1);
        __syncthreads();
        for (int i = t; i < nbuck; i += 256)
            if (lh[i]) lbase[i] = i * CAP + atomicAdd(&bcur[i], lh[i]);
        __syncthreads();
        for (int e = base + t; e < E; e += 256) {
            int d = dst[e];
            int b = d >> BUCKET_SHIFT;
            int pos = lbase[b] + atomicAdd(&lc[b], 1);
            if (pos < (b + 1) * CAP)
                staging[pos] = src[e] | ((d & (BUCKET_SIZE - 1)) << 24);
        }
    }
}

// ---------------- per-bucket counting sort -> CSR (window staged in LDS) ----
__global__ __launch_bounds__(BUCKET_SIZE) void k_bcsr(
        const int* __restrict__ staging, const int* __restrict__ bcur,
        int* __restrict__ esrc, int* __restrict__ rowstart,
        int* __restrict__ deg, int N) {
    __shared__ int sw[CAP];            // 18.4KB window copy
    __shared__ int lh[BUCKET_SIZE];
    __shared__ int lcur[BUCKET_SIZE];
    __shared__ int wsum[4];
    int b = blockIdx.x;
    int s = b * CAP;
    int e = s + min(bcur[b], CAP);     // bcur is a relative count
    int len = e - s;
    int t = threadIdx.x;
    lh[t] = 0;
    __syncthreads();
    for (int i = t; i < len; i += BUCKET_SIZE) {
        int p = staging[s + i];
        sw[i] = p;
        atomicAdd(&lh[((unsigned)p) >> 24], 1);
    }
    __syncthreads();
    int v = lh[t];
    // wave64 inclusive scan (no barriers) + 4-wave combine (1 barrier)
    int lane = t & 63;
    int wv = t >> 6;
    int inc = v;
    #pragma unroll
    for (int off = 1; off < 64; off <<= 1) {
        int x = __shfl_up(inc, off, 64);
        if (lane >= off) inc += x;
    }
    if (lane == 63) wsum[wv] = inc;
    __syncthreads();
    int woff = 0;
    #pragma unroll
    for (int k = 0; k < 3; ++k)
        if (k < wv) woff += wsum[k];
    int excl = woff + inc - v;
    int node = b * BUCKET_SIZE + t;
    if (node < N) { rowstart[node] = s + excl; deg[node] = v; }
    lcur[t] = excl;
    __syncthreads();
    for (int i = t; i < len; i += BUCKET_SIZE) {
        int p = sw[i];
        int local = ((unsigned)p) >> 24;
        int pos = atomicAdd(&lcur[local], 1);
        esrc[s + pos] = p & 0xFFFFFF;
    }
}

// ---------------- GEMM1: A = fp8(x @ W1h^T + b1) ----------------------------
// R12's verified form: 512 threads = 8 waves; 256-node block = 2x 128-node
// tiles sharing one sW stage (fp16 pre-converted W).
__global__ __launch_bounds__(512) void k_gemm(const float* __restrict__ in,
                                              const _Float16* __restrict__ Wh,
                                              const float* __restrict__ bias,
                                              unsigned char* __restrict__ out8,
                                              int N) {
    __shared__ _Float16 sX[128 * LSTR];
    __shared__ _Float16 sW[128 * LSTR];
    int t = threadIdx.x;

    // stage W once (fp16 source, 8B loads/stores, conflict-free)
    #pragma unroll
    for (int it = 0; it < 8; ++it) {
        int lin = it * 512 + t;
        int r = lin >> 5;          // row 0..127
        int c = (lin & 31) * 4;    // col 0..124
        *(half4v*)&sW[r * LSTR + c] = *(const half4v*)(Wh + r * 128 + c);
    }

    int w = t >> 6;            // wave 0..7 -> nodes w*16..w*16+15
    int lane = t & 63;
    int quad = lane >> 4;      // 0..3
    int lrow = lane & 15;      // 0..15

    #pragma unroll
    for (int tile = 0; tile < 2; ++tile) {
        int n0 = blockIdx.x * 256 + tile * 128;
        __syncthreads();   // sX free of previous readers; also fences W-stage
        #pragma unroll
        for (int it = 0; it < 8; ++it) {
            int lin = it * 512 + t;
            int r = lin >> 5;
            int c = (lin & 31) * 4;
            half4v xh = {0, 0, 0, 0};
            int n = n0 + r;
            if (n < N) {
                float4 xv = *(const float4*)(in + (size_t)n * 128 + c);
                xh = half4v{ (_Float16)xv.x, (_Float16)xv.y, (_Float16)xv.z, (_Float16)xv.w };
            }
            *(half4v*)&sX[r * LSTR + c] = xh;
        }
        __syncthreads();

        floatx4 acc[8];
        #pragma unroll
        for (int i = 0; i < 8; ++i) acc[i] = {0.f, 0.f, 0.f, 0.f};

        int arow = (w * 16 + lrow) * LSTR + quad * 8;
        #pragma unroll
        for (int k0 = 0; k0 < 128; k0 += 32) {
            half8 a = *(const half8*)&sX[arow + k0];
            #pragma unroll
            for (int ht = 0; ht < 8; ++ht) {
                half8 bfr = *(const half8*)&sW[(ht * 16 + lrow) * LSTR + quad * 8 + k0];
                acc[ht] = __builtin_amdgcn_mfma_f32_16x16x32_f16(a, bfr, acc[ht], 0, 0, 0);
            }
        }

        // epilogue: C/D col=lane&15 (h), row=quad*4+reg (node); fp8 stores
        #pragma unroll
        for (int ht = 0; ht < 8; ++ht) {
            int h = ht * 16 + lrow;
            float bv = bias[h];
            #pragma unroll
            for (int r = 0; r < 4; ++r) {
                int node = n0 + w * 16 + quad * 4 + r;
                if (node < N) {
                    float v = acc[ht][r] + bv;
                    int pk = __builtin_amdgcn_cvt_pk_fp8_f32(v, v, 0, false);
                    out8[(size_t)node * 128 + h] = (unsigned char)(pk & 0xFF);
                }
            }
        }
    }
}

// ---------------- FUSED agg1 + gemm2 (wave-level): A -> LDS -> A2 -----------
// Each wave owns 16 consecutive nodes: gather-mean-relu each node (floor-form
// scalar-index gather) into the wave's PRIVATE 16-row LDS slice, one 4-wave
// barrier, then the wave runs its own 16x128 W2-MFMA -> A2 (fp8). h1 (B)
// never touches HBM. 256 thr, 17.4KB LDS -> 8 blocks/CU = 32 waves/CU.
__global__ __launch_bounds__(256) void k_agf(const unsigned char* __restrict__ in8,
                                             const int* __restrict__ esrc,
                                             const int* __restrict__ rowstart,
                                             const int* __restrict__ deg,
                                             const _Float16* __restrict__ w2h,
                                             const float* __restrict__ b2,
                                             unsigned char* __restrict__ out8,
                                             int N) {
    __shared__ _Float16 sX[64 * LSTR];   // 4 waves x 16 rows
    int t = threadIdx.x;
    int w = t >> 6;
    int lane = t & 63;
    int n0 = blockIdx.x * 64 + w * 16;   // wave's first node
    const unsigned short* in16 = (const unsigned short*)in8;

    for (int k = 0; k < 16; ++k) {
        int node = n0 + k;               // wave-uniform
        float sx = 0.f, sy = 0.f;
        int dd = 0;
        if (node < N) {
            int start = RFL(rowstart[node]);
            int d     = RFL(deg[node]);
            dd = d;
            floatx2 a0 = {0.f, 0.f}, a1 = {0.f, 0.f}, a2 = {0.f, 0.f}, a3 = {0.f, 0.f};
            int i = 0;
            for (; i + 8 <= d; i += 8) {
                int x0 = RFL(esrc[start + i + 0]);
                int x1 = RFL(esrc[start + i + 1]);
                int x2 = RFL(esrc[start + i + 2]);
                int x3 = RFL(esrc[start + i + 3]);
                int x4 = RFL(esrc[start + i + 4]);
                int x5 = RFL(esrc[start + i + 5]);
                int x6 = RFL(esrc[start + i + 6]);
                int x7 = RFL(esrc[start + i + 7]);
                unsigned u0 = in16[((size_t)x0 << 6) + lane];
                unsigned u1 = in16[((size_t)x1 << 6) + lane];
                unsigned u2 = in16[((size_t)x2 << 6) + lane];
                unsigned u3 = in16[((size_t)x3 << 6) + lane];
                unsigned u4 = in16[((size_t)x4 << 6) + lane];
                unsigned u5 = in16[((size_t)x5 << 6) + lane];
                unsigned u6 = in16[((size_t)x6 << 6) + lane];
                unsigned u7 = in16[((size_t)x7 << 6) + lane];
                floatx2 f0 = __builtin_amdgcn_cvt_pk_f32_fp8(u0, false);
                floatx2 f1 = __builtin_amdgcn_cvt_pk_f32_fp8(u1, false);
                floatx2 f2 = __builtin_amdgcn_cvt_pk_f32_fp8(u2, false);
                floatx2 f3 = __builtin_amdgcn_cvt_pk_f32_fp8(u3, false);
                floatx2 f4 = __builtin_amdgcn_cvt_pk_f32_fp8(u4, false);
                floatx2 f5 = __builtin_amdgcn_cvt_pk_f32_fp8(u5, false);
                floatx2 f6 = __builtin_amdgcn_cvt_pk_f32_fp8(u6, false);
                floatx2 f7 = __builtin_amdgcn_cvt_pk_f32_fp8(u7, false);
                a0.x += f0.x; a0.y += f0.y;  a1.x += f1.x; a1.y += f1.y;
                a2.x += f2.x; a2.y += f2.y;  a3.x += f3.x; a3.y += f3.y;
                a0.x += f4.x; a0.y += f4.y;  a1.x += f5.x; a1.y += f5.y;
                a2.x += f6.x; a2.y += f6.y;  a3.x += f7.x; a3.y += f7.y;
            }
            for (; i + 4 <= d; i += 4) {
                int x0 = RFL(esrc[start + i + 0]);
                int x1 = RFL(esrc[start + i + 1]);
                int x2 = RFL(esrc[start + i + 2]);
                int x3 = RFL(esrc[start + i + 3]);
                unsigned u0 = in16[((size_t)x0 << 6) + lane];
                unsigned u1 = in16[((size_t)x1 << 6) + lane];
                unsigned u2 = in16[((size_t)x2 << 6) + lane];
                unsigned u3 = in16[((size_t)x3 << 6) + lane];
                floatx2 f0 = __builtin_amdgcn_cvt_pk_f32_fp8(u0, false);
                floatx2 f1 = __builtin_amdgcn_cvt_pk_f32_fp8(u1, false);
                floatx2 f2 = __builtin_amdgcn_cvt_pk_f32_fp8(u2, false);
                floatx2 f3 = __builtin_amdgcn_cvt_pk_f32_fp8(u3, false);
                a0.x += f0.x; a0.y += f0.y;  a1.x += f1.x; a1.y += f1.y;
                a2.x += f2.x; a2.y += f2.y;  a3.x += f3.x; a3.y += f3.y;
            }
            for (; i < d; ++i) {
                int x0 = RFL(esrc[start + i]);
                unsigned u0 = in16[((size_t)x0 << 6) + lane];
                floatx2 f0 = __builtin_amdgcn_cvt_pk_f32_fp8(u0, false);
                a0.x += f0.x; a0.y += f0.y;
            }
            sx = (a0.x + a1.x) + (a2.x + a3.x);
            sy = (a0.y + a1.y) + (a2.y + a3.y);
        }
        float dm = fmaxf((float)dd, 1.0f);
        half2v hv = { (_Float16)fmaxf(sx / dm, 0.f),
                      (_Float16)fmaxf(sy / dm, 0.f) };
        *(half2v*)&sX[(w * 16 + k) * LSTR + lane * 2] = hv;
    }
    __syncthreads();   // 4-wave block; fences LDS rows for MFMA reads

    // wave-level 16x128 MFMA vs W2 (B-fragments direct from global, L2-hot)
    int quad = lane >> 4;
    int lrow = lane & 15;
    floatx4 acc[8];
    #pragma unroll
    for (int i = 0; i < 8; ++i) acc[i] = {0.f, 0.f, 0.f, 0.f};

    int arow = (w * 16 + lrow) * LSTR + quad * 8;
    #pragma unroll
    for (int k0 = 0; k0 < 128; k0 += 32) {
        half8 a = *(const half8*)&sX[arow + k0];
        #pragma unroll
        for (int ht = 0; ht < 8; ++ht) {
            half8 b = *(const half8*)(w2h + (ht * 16 + lrow) * 128 + quad * 8 + k0);
            acc[ht] = __builtin_amdgcn_mfma_f32_16x16x32_f16(a, b, acc[ht], 0, 0, 0);
        }
    }
    // epilogue: C/D col=lane&15 (h), row=quad*4+reg within the 16-row tile
    #pragma unroll
    for (int ht = 0; ht < 8; ++ht) {
        int h = ht * 16 + lrow;
        float bv = b2[h];
        #pragma unroll
        for (int r = 0; r < 4; ++r) {
            int node = n0 + quad * 4 + r;
            if (node < N) {
                float v = acc[ht][r] + bv;
                int pk = __builtin_amdgcn_cvt_pk_fp8_f32(v, v, 0, false);
                out8[(size_t)node * 128 + h] = (unsigned char)(pk & 0xFF);
            }
        }
    }
}

// ---------------- FUSED aggregation 2 + segment-max pool (R17 verified) -----
// Waves independent; 16-node spans; running max in regs; per-span atomicMax.
__global__ __launch_bounds__(256) void k_aggp2(const unsigned char* __restrict__ in8,
                                               const int* __restrict__ esrc,
                                               const int* __restrict__ rowstart,
                                               const int* __restrict__ deg,
                                               const int* __restrict__ batch,
                                               float* __restrict__ pm, int N) {
    int lane = threadIdx.x & 63;
    int gw = blockIdx.x * 4 + (threadIdx.x >> 6);
    int n0 = gw * 16;
    if (n0 >= N) return;
    int nend = min(n0 + 16, N);
    const unsigned short* in16 = (const unsigned short*)in8;

    int curg = RFL(batch[n0]);
    float mx = 0.f, my = 0.f;        // relu'd values are >= 0

    for (int node = n0; node < nend; ++node) {
        int g = RFL(batch[node]);
        if (g != curg) {
            int* pmi = (int*)(pm + (size_t)curg * 128 + lane * 2);
            atomicMax(pmi,     __float_as_int(mx));
            atomicMax(pmi + 1, __float_as_int(my));
            curg = g; mx = 0.f; my = 0.f;
        }
        int start = RFL(rowstart[node]);
        int d     = RFL(deg[node]);
        floatx2 a0 = {0.f, 0.f}, a1 = {0.f, 0.f}, a2 = {0.f, 0.f}, a3 = {0.f, 0.f};
        int i = 0;
        for (; i + 8 <= d; i += 8) {
            int x0 = RFL(esrc[start + i + 0]);
            int x1 = RFL(esrc[start + i + 1]);
            int x2 = RFL(esrc[start + i + 2]);
            int x3 = RFL(esrc[start + i + 3]);
            int x4 = RFL(esrc[start + i + 4]);
            int x5 = RFL(esrc[start + i + 5]);
            int x6 = RFL(esrc[start + i + 6]);
            int x7 = RFL(esrc[start + i + 7]);
            unsigned u0 = in16[((size_t)x0 << 6) + lane];
            unsigned u1 = in16[((size_t)x1 << 6) + lane];
            unsigned u2 = in16[((size_t)x2 << 6) + lane];
            unsigned u3 = in16[((size_t)x3 << 6) + lane];
            unsigned u4 = in16[((size_t)x4 << 6) + lane];
            unsigned u5 = in16[((size_t)x5 << 6) + lane];
            unsigned u6 = in16[((size_t)x6 << 6) + lane];
            unsigned u7 = in16[((size_t)x7 << 6) + lane];
            floatx2 f0 = __builtin_amdgcn_cvt_pk_f32_fp8(u0, false);
            floatx2 f1 = __builtin_amdgcn_cvt_pk_f32_fp8(u1, false);
            floatx2 f2 = __builtin_amdgcn_cvt_pk_f32_fp8(u2, false);
            floatx2 f3 = __builtin_amdgcn_cvt_pk_f32_fp8(u3, false);
            floatx2 f4 = __builtin_amdgcn_cvt_pk_f32_fp8(u4, false);
            floatx2 f5 = __builtin_amdgcn_cvt_pk_f32_fp8(u5, false);
            floatx2 f6 = __builtin_amdgcn_cvt_pk_f32_fp8(u6, false);
            floatx2 f7 = __builtin_amdgcn_cvt_pk_f32_fp8(u7, false);
            a0.x += f0.x; a0.y += f0.y;  a1.x += f1.x; a1.y += f1.y;
            a2.x += f2.x; a2.y += f2.y;  a3.x += f3.x; a3.y += f3.y;
            a0.x += f4.x; a0.y += f4.y;  a1.x += f5.x; a1.y += f5.y;
            a2.x += f6.x; a2.y += f6.y;  a3.x += f7.x; a3.y += f7.y;
        }
        for (; i + 4 <= d; i += 4) {
            int x0 = RFL(esrc[start + i + 0]);
            int x1 = RFL(esrc[start + i + 1]);
            int x2 = RFL(esrc[start + i + 2]);
            int x3 = RFL(esrc[start + i + 3]);
            unsigned u0 = in16[((size_t)x0 << 6) + lane];
            unsigned u1 = in16[((size_t)x1 << 6) + lane];
            unsigned u2 = in16[((size_t)x2 << 6) + lane];
            unsigned u3 = in16[((size_t)x3 << 6) + lane];
            floatx2 f0 = __builtin_amdgcn_cvt_pk_f32_fp8(u0, false);
            floatx2 f1 = __builtin_amdgcn_cvt_pk_f32_fp8(u1, false);
            floatx2 f2 = __builtin_amdgcn_cvt_pk_f32_fp8(u2, false);
            floatx2 f3 = __builtin_amdgcn_cvt_pk_f32_fp8(u3, false);
            a0.x += f0.x; a0.y += f0.y;  a1.x += f1.x; a1.y += f1.y;
            a2.x += f2.x; a2.y += f2.y;  a3.x += f3.x; a3.y += f3.y;
        }
        for (; i < d; ++i) {
            int x0 = RFL(esrc[start + i]);
            unsigned u0 = in16[((size_t)x0 << 6) + lane];
            floatx2 f0 = __builtin_amdgcn_cvt_pk_f32_fp8(u0, false);
            a0.x += f0.x; a0.y += f0.y;
        }
        float sx = (a0.x + a1.x) + (a2.x + a3.x);
        float sy = (a0.y + a1.y) + (a2.y + a3.y);
        float dm = fmaxf((float)d, 1.0f);
        mx = fmaxf(mx, fmaxf(sx / dm, 0.f));
        my = fmaxf(my, fmaxf(sy / dm, 0.f));
    }
    int* pmi = (int*)(pm + (size_t)curg * 128 + lane * 2);
    atomicMax(pmi,     __float_as_int(mx));
    atomicMax(pmi + 1, __float_as_int(my));
}

// ---------------- final: FC1(relu) + FC2 + log_softmax (pm direct) ----------
__global__ void k_fc(const float* __restrict__ pm,
                     const float* __restrict__ Wf1, const float* __restrict__ bf1,
                     const float* __restrict__ Wf2, const float* __restrict__ bf2,
                     float* __restrict__ out) {
    __shared__ float sg[128];
    __shared__ float sz[128];
    __shared__ float so[2];
    int g = blockIdx.x;
    int t = threadIdx.x;
    sg[t] = pm[(size_t)g * 128 + t];
    __syncthreads();
    float z = bf1[t];
    #pragma unroll 4
    for (int d = 0; d < 128; ++d)
        z += sg[d] * Wf1[t * 128 + d];
    sz[t] = fmaxf(z, 0.f);
    __syncthreads();
    if (t < 2) {
        float o = bf2[t];
        for (int d = 0; d < 128; ++d)
            o += sz[d] * Wf2[t * 128 + d];
        so[t] = o;
    }
    __syncthreads();
    if (t == 0) {
        float a = so[0], b = so[1];
        float mx = fmaxf(a, b);
        float ls = mx + logf(expf(a - mx) + expf(b - mx));
        out[g * 2 + 0] = a - ls;
        out[g * 2 + 1] = b - ls;
    }
}

extern "C" void kernel_launch(void* const* d_in, const int* in_sizes, int n_in,
                              void* d_out, int out_size, void* d_ws, size_t ws_size,
                              hipStream_t stream) {
    const float* x   = (const float*)d_in[0];
    const int*   ei  = (const int*)d_in[1];
    const int* batch = (const int*)d_in[2];
    const float* W1  = (const float*)d_in[3];
    const float* b1  = (const float*)d_in[4];
    const float* W2  = (const float*)d_in[5];
    const float* b2  = (const float*)d_in[6];
    const float* Wf1 = (const float*)d_in[7];
    const float* bf1 = (const float*)d_in[8];
    const float* Wf2 = (const float*)d_in[9];
    const float* bf2 = (const float*)d_in[10];

    int N = in_sizes[2];
    int E = in_sizes[1] / 2;
    int G = out_size / 2;
    const int* src = ei;
    const int* dst = ei + E;
    int nbuck = (N + BUCKET_SIZE - 1) / BUCKET_SIZE;   // 391

    // workspace carve-out (256B aligned). bcur/gstart/gend/pm contiguous ->
    // one hipMemsetAsync zeroes all of them.
    char* p = (char*)d_ws;
    auto alloc = [&](size_t bytes) -> char* {
        char* r = p;
        p += (bytes + 255) & ~(size_t)255;
        return r;
    };
    unsigned char* A  = (unsigned char*)alloc((size_t)N * 128);  // fp8 msg (layer1)
    unsigned char* A2 = (unsigned char*)alloc((size_t)N * 128);  // fp8 msg (layer2)
    int* deg       = (int*)alloc((size_t)N * 4);
    int* rowstart  = (int*)alloc((size_t)N * 4);
    int* esrc      = (int*)alloc((size_t)nbuck * CAP * 4);       // windowed CSR
    int* staging   = (int*)alloc((size_t)nbuck * CAP * 4);
    _Float16* w1h  = (_Float16*)alloc((size_t)128 * 128 * 2);
    _Float16* w2h  = (_Float16*)alloc((size_t)128 * 128 * 2);
    // zeroed region start:
    char* zbase    = p;
    int* bcur      = (int*)alloc((size_t)MAXBUCK * 4);           // relative counts
    int* gstart    = (int*)alloc((size_t)G * 4);
    int* gend      = (int*)alloc((size_t)G * 4);
    float* pm      = (float*)alloc((size_t)G * 128 * 4);         // pooled max [G,128]
    size_t zbytes  = (size_t)(p - zbase);

    int nchunk = (E + BIN_CHUNK - 1) / BIN_CHUNK;      // 391 (covers N too)

    // memset -> bin -> bcsr -> gemm1 -> agf(agg1+gemm2) -> aggp2(agg2+pool) -> fc
    hipMemsetAsync(zbase, 0, zbytes, stream);
    k_bin<<<nchunk, 256, 0, stream>>>(src, dst, bcur, staging, batch,
                                      gstart, gend, W1, W2, w1h, w2h,
                                      E, N, nbuck);
    k_bcsr<<<nbuck, BUCKET_SIZE, 0, stream>>>(staging, bcur, esrc, rowstart, deg, N);

    k_gemm<<<(N + 255) / 256, 512, 0, stream>>>(x, w1h, b1, A, N);
    k_agf<<<(N + 63) / 64, 256, 0, stream>>>(A, esrc, rowstart, deg, w2h, b2, A2, N);
    k_aggp2<<<(N + 63) / 64, 256, 0, stream>>>(A2, esrc, rowstart, deg, batch, pm, N);
    k_fc<<<G, 128, 0, stream>>>(pm, Wf1, bf1, Wf2, bf2, (float*)d_out);
}

// Round 14
// 283.992 us; speedup vs baseline: 1.1410x; 1.1410x over previous
//
#include <hip/hip_runtime.h>
#include <hip/hip_fp16.h>
#include <math.h>

// 2-layer GNN (linear -> gather -> scatter-mean -> relu) x2, segment-max
// pool over 64 graphs, FC head, log_softmax. N=100k, E=1.6M, D=H=128, G=64.
//
// R18 -> R19: REVERT to R17 (284.1us, session best). k_agf wave-fusion
// failed its falsifier (105.7us: occupancy 32% from VGPR+LDS+acc footprint,
// 4-wave straggler coupling, LDS conflicts). Sixth structural failure;
// law of this workload: the gather is latency-hiding-limited — any fusion
// that costs occupancy or couples waves loses more than it saves. R17's
// aggp2 is the one fusion that works (waves independent, register state,
// sparse atomic flush, no MFMA/LDS). All kernels at verified floors:
// agg 42.9 (compulsory traffic), aggp2 51.4, gemm ~10ea, CSR ~33,
// launches dependency-minimal (6 + memset). Next stop: roofline.

#define BUCKET_SHIFT 8
#define BUCKET_SIZE 256
#define MAXBUCK 512     // >= nbuck = ceil(N/256) = 391
#define BIN_CHUNK 4096
#define CAP 4608        // bucket window capacity; mean 4092 -> +8 sigma
#define LSTR 136        // LDS row stride in halves (272B): %8==0 for b128

typedef _Float16 half8 __attribute__((ext_vector_type(8)));
typedef _Float16 half4v __attribute__((ext_vector_type(4)));
typedef _Float16 half2v __attribute__((ext_vector_type(2)));
typedef float floatx4 __attribute__((ext_vector_type(4)));
typedef float floatx2 __attribute__((ext_vector_type(2)));

#define RFL(v) __builtin_amdgcn_readfirstlane(v)

// ---------------- multisplit binning + bounds + W-convert -------------------
// pack: low 24 bits = src (N < 2^24), high 8 bits = dst & 255
// bcur starts 0 (memset); window base i*CAP added locally.
__global__ __launch_bounds__(256) void k_bin(
        const int* __restrict__ src, const int* __restrict__ dst,
        int* __restrict__ bcur, int* __restrict__ staging,
        const int* __restrict__ batch, int* __restrict__ gstart,
        int* __restrict__ gend,
        const float* __restrict__ W1, const float* __restrict__ W2,
        _Float16* __restrict__ w1h, _Float16* __restrict__ w2h,
        int E, int N, int nbuck) {
    __shared__ int lh[MAXBUCK];
    __shared__ int lbase[MAXBUCK];
    __shared__ int lc[MAXBUCK];
    int t = threadIdx.x;
    for (int i = t; i < nbuck; i += 256) { lh[i] = 0; lc[i] = 0; }

    // folded W -> fp16 convert: blocks 0..63 x 256 threads = 16384 = 128*128
    if (blockIdx.x < 64) {
        int i = blockIdx.x * 256 + t;
        w1h[i] = (_Float16)W1[i];
        w2h[i] = (_Float16)W2[i];
    }

    // fused k_bounds: 391 blocks x 256 threads >= N
    int n = blockIdx.x * 256 + t;
    if (n < N) {
        int b = batch[n];
        if (n == 0 || batch[n - 1] != b) gstart[b] = n;
        if (n == N - 1 || batch[n + 1] != b) gend[b] = n + 1;
    }
    __syncthreads();

    int base = blockIdx.x * BIN_CHUNK;
    if (base + BIN_CHUNK <= E) {
        // full chunk: 16 edges/thread in registers, int4 coalesced loads
        int ds[16], ss[16];
        const int4* dv = (const int4*)(dst + base);
        const int4* sv = (const int4*)(src + base);
        #pragma unroll
        for (int j = 0; j < 4; ++j) {
            int4 d = dv[j * 256 + t];
            int4 s = sv[j * 256 + t];
            ds[j * 4 + 0] = d.x; ds[j * 4 + 1] = d.y;
            ds[j * 4 + 2] = d.z; ds[j * 4 + 3] = d.w;
            ss[j * 4 + 0] = s.x; ss[j * 4 + 1] = s.y;
            ss[j * 4 + 2] = s.z; ss[j * 4 + 3] = s.w;
        }
        #pragma unroll
        for (int q = 0; q < 16; ++q)
            atomicAdd(&lh[ds[q] >> BUCKET_SHIFT], 1);
        __syncthreads();
        for (int i = t; i < nbuck; i += 256)
            if (lh[i]) lbase[i] = i * CAP + atomicAdd(&bcur[i], lh[i]);
        __syncthreads();
        #pragma unroll
        for (int q = 0; q < 16; ++q) {
            int d = ds[q];
            int b = d >> BUCKET_SHIFT;
            int pos = lbase[b] + atomicAdd(&lc[b], 1);
            if (pos < (b + 1) * CAP)   // overflow guard
                staging[pos] = ss[q] | ((d & (BUCKET_SIZE - 1)) << 24);
        }
    } else {
        // tail chunk (last block only): scalar path
        for (int e = base + t; e < E; e += 256)
            atomicAdd(&lh[dst[e] >> BUCKET_SHIFT], 1);
        __syncthreads();
        for (int i = t; i < nbuck; i += 256)
            if (lh[i]) lbase[i] = i * CAP + atomicAdd(&bcur[i], lh[i]);
        __syncthreads();
        for (int e = base + t; e < E; e += 256) {
            int d = dst[e];
            int b = d >> BUCKET_SHIFT;
            int pos = lbase[b] + atomicAdd(&lc[b], 1);
            if (pos < (b + 1) * CAP)
                staging[pos] = src[e] | ((d & (BUCKET_SIZE - 1)) << 24);
        }
    }
}

// ---------------- per-bucket counting sort -> CSR (window staged in LDS) ----
__global__ __launch_bounds__(BUCKET_SIZE) void k_bcsr(
        const int* __restrict__ staging, const int* __restrict__ bcur,
        int* __restrict__ esrc, int* __restrict__ rowstart,
        int* __restrict__ deg, int N) {
    __shared__ int sw[CAP];            // 18.4KB window copy
    __shared__ int lh[BUCKET_SIZE];
    __shared__ int lcur[BUCKET_SIZE];
    __shared__ int wsum[4];
    int b = blockIdx.x;
    int s = b * CAP;
    int e = s + min(bcur[b], CAP);     // bcur is a relative count now
    int len = e - s;
    int t = threadIdx.x;
    lh[t] = 0;
    __syncthreads();
    for (int i = t; i < len; i += BUCKET_SIZE) {
        int p = staging[s + i];
        sw[i] = p;
        atomicAdd(&lh[((unsigned)p) >> 24], 1);
    }
    __syncthreads();
    int v = lh[t];
    // wave64 inclusive scan (no barriers) + 4-wave combine (1 barrier)
    int lane = t & 63;
    int wv = t >> 6;
    int inc = v;
    #pragma unroll
    for (int off = 1; off < 64; off <<= 1) {
        int x = __shfl_up(inc, off, 64);
        if (lane >= off) inc += x;
    }
    if (lane == 63) wsum[wv] = inc;
    __syncthreads();
    int woff = 0;
    #pragma unroll
    for (int k = 0; k < 3; ++k)
        if (k < wv) woff += wsum[k];
    int excl = woff + inc - v;
    int node = b * BUCKET_SIZE + t;
    if (node < N) { rowstart[node] = s + excl; deg[node] = v; }
    lcur[t] = excl;
    __syncthreads();
    for (int i = t; i < len; i += BUCKET_SIZE) {
        int p = sw[i];
        int local = ((unsigned)p) >> 24;
        int pos = atomicAdd(&lcur[local], 1);
        esrc[s + pos] = p & 0xFFFFFF;
    }
}

// ---------------- MFMA GEMM: out8[n,h] = fp8(bias[h] + sum_d in[n,d]*W[h,d]) ----
// R12's verified form: 512 threads = 8 waves; 256-node block = 2x 128-node
// tiles sharing one sW stage (fp16 pre-converted W).
template <typename T>
__global__ __launch_bounds__(512) void k_gemm(const T* __restrict__ in,
                                              const _Float16* __restrict__ Wh,
                                              const float* __restrict__ bias,
                                              unsigned char* __restrict__ out8,
                                              int N) {
    __shared__ _Float16 sX[128 * LSTR];
    __shared__ _Float16 sW[128 * LSTR];
    int t = threadIdx.x;

    // stage W once (fp16 source, 8B loads/stores, conflict-free)
    #pragma unroll
    for (int it = 0; it < 8; ++it) {
        int lin = it * 512 + t;
        int r = lin >> 5;          // row 0..127
        int c = (lin & 31) * 4;    // col 0..124
        *(half4v*)&sW[r * LSTR + c] = *(const half4v*)(Wh + r * 128 + c);
    }

    int w = t >> 6;            // wave 0..7 -> nodes w*16..w*16+15
    int lane = t & 63;
    int quad = lane >> 4;      // 0..3
    int lrow = lane & 15;      // 0..15

    #pragma unroll
    for (int tile = 0; tile < 2; ++tile) {
        int n0 = blockIdx.x * 256 + tile * 128;
        __syncthreads();   // sX free of previous readers; also fences W-stage
        #pragma unroll
        for (int it = 0; it < 8; ++it) {
            int lin = it * 512 + t;
            int r = lin >> 5;
            int c = (lin & 31) * 4;
            half4v xh = {0, 0, 0, 0};
            int n = n0 + r;
            if (n < N) {
                if constexpr (sizeof(T) == 4) {
                    float4 xv = *(const float4*)((const float*)in + (size_t)n * 128 + c);
                    xh = half4v{ (_Float16)xv.x, (_Float16)xv.y, (_Float16)xv.z, (_Float16)xv.w };
                } else {
                    xh = *(const half4v*)((const _Float16*)in + (size_t)n * 128 + c);
                }
            }
            *(half4v*)&sX[r * LSTR + c] = xh;
        }
        __syncthreads();

        floatx4 acc[8];
        #pragma unroll
        for (int i = 0; i < 8; ++i) acc[i] = {0.f, 0.f, 0.f, 0.f};

        int arow = (w * 16 + lrow) * LSTR + quad * 8;
        #pragma unroll
        for (int k0 = 0; k0 < 128; k0 += 32) {
            half8 a = *(const half8*)&sX[arow + k0];
            #pragma unroll
            for (int ht = 0; ht < 8; ++ht) {
                half8 bfr = *(const half8*)&sW[(ht * 16 + lrow) * LSTR + quad * 8 + k0];
                acc[ht] = __builtin_amdgcn_mfma_f32_16x16x32_f16(a, bfr, acc[ht], 0, 0, 0);
            }
        }

        // epilogue: C/D col=lane&15 (h), row=quad*4+reg (node); fp8 stores
        #pragma unroll
        for (int ht = 0; ht < 8; ++ht) {
            int h = ht * 16 + lrow;
            float bv = bias[h];
            #pragma unroll
            for (int r = 0; r < 4; ++r) {
                int node = n0 + w * 16 + quad * 4 + r;
                if (node < N) {
                    float v = acc[ht][r] + bv;
                    int pk = __builtin_amdgcn_cvt_pk_fp8_f32(v, v, 0, false);
                    out8[(size_t)node * 128 + h] = (unsigned char)(pk & 0xFF);
                }
            }
        }
    }
}

// ---------------- aggregation 1: B[n] = relu(mean gather A) -----------------
// ONE NODE PER WAVE64 (verified 42.9us floor form). fp16 output to B.
__global__ __launch_bounds__(256) void k_agg(const unsigned char* __restrict__ in8,
                                             const int* __restrict__ esrc,
                                             const int* __restrict__ rowstart,
                                             const int* __restrict__ deg,
                                             _Float16* __restrict__ outh, int N) {
    int lane = threadIdx.x & 63;
    int node = blockIdx.x * 4 + (threadIdx.x >> 6);
    if (node >= N) return;
    int start = RFL(rowstart[node]);
    int d     = RFL(deg[node]);
    const unsigned short* in16 = (const unsigned short*)in8;

    floatx2 a0 = {0.f, 0.f}, a1 = {0.f, 0.f}, a2 = {0.f, 0.f}, a3 = {0.f, 0.f};

    int i = 0;
    for (; i + 8 <= d; i += 8) {
        int x0 = RFL(esrc[start + i + 0]);
        int x1 = RFL(esrc[start + i + 1]);
        int x2 = RFL(esrc[start + i + 2]);
        int x3 = RFL(esrc[start + i + 3]);
        int x4 = RFL(esrc[start + i + 4]);
        int x5 = RFL(esrc[start + i + 5]);
        int x6 = RFL(esrc[start + i + 6]);
        int x7 = RFL(esrc[start + i + 7]);
        unsigned u0 = in16[((size_t)x0 << 6) + lane];
        unsigned u1 = in16[((size_t)x1 << 6) + lane];
        unsigned u2 = in16[((size_t)x2 << 6) + lane];
        unsigned u3 = in16[((size_t)x3 << 6) + lane];
        unsigned u4 = in16[((size_t)x4 << 6) + lane];
        unsigned u5 = in16[((size_t)x5 << 6) + lane];
        unsigned u6 = in16[((size_t)x6 << 6) + lane];
        unsigned u7 = in16[((size_t)x7 << 6) + lane];
        floatx2 f0 = __builtin_amdgcn_cvt_pk_f32_fp8(u0, false);
        floatx2 f1 = __builtin_amdgcn_cvt_pk_f32_fp8(u1, false);
        floatx2 f2 = __builtin_amdgcn_cvt_pk_f32_fp8(u2, false);
        floatx2 f3 = __builtin_amdgcn_cvt_pk_f32_fp8(u3, false);
        floatx2 f4 = __builtin_amdgcn_cvt_pk_f32_fp8(u4, false);
        floatx2 f5 = __builtin_amdgcn_cvt_pk_f32_fp8(u5, false);
        floatx2 f6 = __builtin_amdgcn_cvt_pk_f32_fp8(u6, false);
        floatx2 f7 = __builtin_amdgcn_cvt_pk_f32_fp8(u7, false);
        a0.x += f0.x; a0.y += f0.y;  a1.x += f1.x; a1.y += f1.y;
        a2.x += f2.x; a2.y += f2.y;  a3.x += f3.x; a3.y += f3.y;
        a0.x += f4.x; a0.y += f4.y;  a1.x += f5.x; a1.y += f5.y;
        a2.x += f6.x; a2.y += f6.y;  a3.x += f7.x; a3.y += f7.y;
    }
    for (; i + 4 <= d; i += 4) {
        int x0 = RFL(esrc[start + i + 0]);
        int x1 = RFL(esrc[start + i + 1]);
        int x2 = RFL(esrc[start + i + 2]);
        int x3 = RFL(esrc[start + i + 3]);
        unsigned u0 = in16[((size_t)x0 << 6) + lane];
        unsigned u1 = in16[((size_t)x1 << 6) + lane];
        unsigned u2 = in16[((size_t)x2 << 6) + lane];
        unsigned u3 = in16[((size_t)x3 << 6) + lane];
        floatx2 f0 = __builtin_amdgcn_cvt_pk_f32_fp8(u0, false);
        floatx2 f1 = __builtin_amdgcn_cvt_pk_f32_fp8(u1, false);
        floatx2 f2 = __builtin_amdgcn_cvt_pk_f32_fp8(u2, false);
        floatx2 f3 = __builtin_amdgcn_cvt_pk_f32_fp8(u3, false);
        a0.x += f0.x; a0.y += f0.y;  a1.x += f1.x; a1.y += f1.y;
        a2.x += f2.x; a2.y += f2.y;  a3.x += f3.x; a3.y += f3.y;
    }
    for (; i < d; ++i) {
        int x0 = RFL(esrc[start + i]);
        unsigned u0 = in16[((size_t)x0 << 6) + lane];
        floatx2 f0 = __builtin_amdgcn_cvt_pk_f32_fp8(u0, false);
        a0.x += f0.x; a0.y += f0.y;
    }

    float sx = (a0.x + a1.x) + (a2.x + a3.x);
    float sy = (a0.y + a1.y) + (a2.y + a3.y);
    float dm = fmaxf((float)d, 1.0f);
    half2v r = { (_Float16)fmaxf(sx / dm, 0.f),
                 (_Float16)fmaxf(sy / dm, 0.f) };
    *(half2v*)(outh + (size_t)node * 128 + lane * 2) = r;   // 64x4B = 256B row
}

// ---------------- FUSED aggregation 2 + segment-max pool (safe form) --------
// Waves stay INDEPENDENT (no cross-wave barrier). Each wave owns 16
// consecutive nodes (sorted batch => ~1 graph per span); running max kept
// in 2 regs/lane; flush = 128 atomicMax per SPAN boundary (~800K total).
__global__ __launch_bounds__(256) void k_aggp2(const unsigned char* __restrict__ in8,
                                               const int* __restrict__ esrc,
                                               const int* __restrict__ rowstart,
                                               const int* __restrict__ deg,
                                               const int* __restrict__ batch,
                                               float* __restrict__ pm, int N) {
    int lane = threadIdx.x & 63;
    int gw = blockIdx.x * 4 + (threadIdx.x >> 6);
    int n0 = gw * 16;
    if (n0 >= N) return;
    int nend = min(n0 + 16, N);
    const unsigned short* in16 = (const unsigned short*)in8;

    int curg = RFL(batch[n0]);
    float mx = 0.f, my = 0.f;        // relu'd values are >= 0

    for (int node = n0; node < nend; ++node) {
        int g = RFL(batch[node]);
        if (g != curg) {
            int* pmi = (int*)(pm + (size_t)curg * 128 + lane * 2);
            atomicMax(pmi,     __float_as_int(mx));
            atomicMax(pmi + 1, __float_as_int(my));
            curg = g; mx = 0.f; my = 0.f;
        }
        int start = RFL(rowstart[node]);
        int d     = RFL(deg[node]);
        floatx2 a0 = {0.f, 0.f}, a1 = {0.f, 0.f}, a2 = {0.f, 0.f}, a3 = {0.f, 0.f};
        int i = 0;
        for (; i + 8 <= d; i += 8) {
            int x0 = RFL(esrc[start + i + 0]);
            int x1 = RFL(esrc[start + i + 1]);
            int x2 = RFL(esrc[start + i + 2]);
            int x3 = RFL(esrc[start + i + 3]);
            int x4 = RFL(esrc[start + i + 4]);
            int x5 = RFL(esrc[start + i + 5]);
            int x6 = RFL(esrc[start + i + 6]);
            int x7 = RFL(esrc[start + i + 7]);
            unsigned u0 = in16[((size_t)x0 << 6) + lane];
            unsigned u1 = in16[((size_t)x1 << 6) + lane];
            unsigned u2 = in16[((size_t)x2 << 6) + lane];
            unsigned u3 = in16[((size_t)x3 << 6) + lane];
            unsigned u4 = in16[((size_t)x4 << 6) + lane];
            unsigned u5 = in16[((size_t)x5 << 6) + lane];
            unsigned u6 = in16[((size_t)x6 << 6) + lane];
            unsigned u7 = in16[((size_t)x7 << 6) + lane];
            floatx2 f0 = __builtin_amdgcn_cvt_pk_f32_fp8(u0, false);
            floatx2 f1 = __builtin_amdgcn_cvt_pk_f32_fp8(u1, false);
            floatx2 f2 = __builtin_amdgcn_cvt_pk_f32_fp8(u2, false);
            floatx2 f3 = __builtin_amdgcn_cvt_pk_f32_fp8(u3, false);
            floatx2 f4 = __builtin_amdgcn_cvt_pk_f32_fp8(u4, false);
            floatx2 f5 = __builtin_amdgcn_cvt_pk_f32_fp8(u5, false);
            floatx2 f6 = __builtin_amdgcn_cvt_pk_f32_fp8(u6, false);
            floatx2 f7 = __builtin_amdgcn_cvt_pk_f32_fp8(u7, false);
            a0.x += f0.x; a0.y += f0.y;  a1.x += f1.x; a1.y += f1.y;
            a2.x += f2.x; a2.y += f2.y;  a3.x += f3.x; a3.y += f3.y;
            a0.x += f4.x; a0.y += f4.y;  a1.x += f5.x; a1.y += f5.y;
            a2.x += f6.x; a2.y += f6.y;  a3.x += f7.x; a3.y += f7.y;
        }
        for (; i + 4 <= d; i += 4) {
            int x0 = RFL(esrc[start + i + 0]);
            int x1 = RFL(esrc[start + i + 1]);
            int x2 = RFL(esrc[start + i + 2]);
            int x3 = RFL(esrc[start + i + 3]);
            unsigned u0 = in16[((size_t)x0 << 6) + lane];
            unsigned u1 = in16[((size_t)x1 << 6) + lane];
            unsigned u2 = in16[((size_t)x2 << 6) + lane];
            unsigned u3 = in16[((size_t)x3 << 6) + lane];
            floatx2 f0 = __builtin_amdgcn_cvt_pk_f32_fp8(u0, false);
            floatx2 f1 = __builtin_amdgcn_cvt_pk_f32_fp8(u1, false);
            floatx2 f2 = __builtin_amdgcn_cvt_pk_f32_fp8(u2, false);
            floatx2 f3 = __builtin_amdgcn_cvt_pk_f32_fp8(u3, false);
            a0.x += f0.x; a0.y += f0.y;  a1.x += f1.x; a1.y += f1.y;
            a2.x += f2.x; a2.y += f2.y;  a3.x += f3.x; a3.y += f3.y;
        }
        for (; i < d; ++i) {
            int x0 = RFL(esrc[start + i]);
            unsigned u0 = in16[((size_t)x0 << 6) + lane];
            floatx2 f0 = __builtin_amdgcn_cvt_pk_f32_fp8(u0, false);
            a0.x += f0.x; a0.y += f0.y;
        }
        float sx = (a0.x + a1.x) + (a2.x + a3.x);
        float sy = (a0.y + a1.y) + (a2.y + a3.y);
        float dm = fmaxf((float)d, 1.0f);
        mx = fmaxf(mx, fmaxf(sx / dm, 0.f));
        my = fmaxf(my, fmaxf(sy / dm, 0.f));
    }
    int* pmi = (int*)(pm + (size_t)curg * 128 + lane * 2);
    atomicMax(pmi,     __float_as_int(mx));
    atomicMax(pmi + 1, __float_as_int(my));
}

// ---------------- final: FC1(relu) + FC2 + log_softmax (pm direct) ----------
__global__ void k_fc(const float* __restrict__ pm,
                     const float* __restrict__ Wf1, const float* __restrict__ bf1,
                     const float* __restrict__ Wf2, const float* __restrict__ bf2,
                     float* __restrict__ out) {
    __shared__ float sg[128];
    __shared__ float sz[128];
    __shared__ float so[2];
    int g = blockIdx.x;
    int t = threadIdx.x;
    sg[t] = pm[(size_t)g * 128 + t];
    __syncthreads();
    float z = bf1[t];
    #pragma unroll 4
    for (int d = 0; d < 128; ++d)
        z += sg[d] * Wf1[t * 128 + d];
    sz[t] = fmaxf(z, 0.f);
    __syncthreads();
    if (t < 2) {
        float o = bf2[t];
        for (int d = 0; d < 128; ++d)
            o += sz[d] * Wf2[t * 128 + d];
        so[t] = o;
    }
    __syncthreads();
    if (t == 0) {
        float a = so[0], b = so[1];
        float mx = fmaxf(a, b);
        float ls = mx + logf(expf(a - mx) + expf(b - mx));
        out[g * 2 + 0] = a - ls;
        out[g * 2 + 1] = b - ls;
    }
}

extern "C" void kernel_launch(void* const* d_in, const int* in_sizes, int n_in,
                              void* d_out, int out_size, void* d_ws, size_t ws_size,
                              hipStream_t stream) {
    const float* x   = (const float*)d_in[0];
    const int*   ei  = (const int*)d_in[1];
    const int* batch = (const int*)d_in[2];
    const float* W1  = (const float*)d_in[3];
    const float* b1  = (const float*)d_in[4];
    const float* W2  = (const float*)d_in[5];
    const float* b2  = (const float*)d_in[6];
    const float* Wf1 = (const float*)d_in[7];
    const float* bf1 = (const float*)d_in[8];
    const float* Wf2 = (const float*)d_in[9];
    const float* bf2 = (const float*)d_in[10];

    int N = in_sizes[2];
    int E = in_sizes[1] / 2;
    int G = out_size / 2;
    const int* src = ei;
    const int* dst = ei + E;
    int nbuck = (N + BUCKET_SIZE - 1) / BUCKET_SIZE;   // 391

    // workspace carve-out (256B aligned). NOTE: bcur/gstart/gend/pm are
    // allocated CONTIGUOUSLY so one hipMemsetAsync zeroes all of them.
    char* p = (char*)d_ws;
    auto alloc = [&](size_t bytes) -> char* {
        char* r = p;
        p += (bytes + 255) & ~(size_t)255;
        return r;
    };
    unsigned char* A  = (unsigned char*)alloc((size_t)N * 128);  // fp8 msg (layer1)
    unsigned char* A2 = (unsigned char*)alloc((size_t)N * 128);  // fp8 msg (layer2)
    _Float16* B    = (_Float16*)alloc((size_t)N * 128 * 2);      // fp16 h1 buffer
    int* deg       = (int*)alloc((size_t)N * 4);
    int* rowstart  = (int*)alloc((size_t)N * 4);
    int* esrc      = (int*)alloc((size_t)nbuck * CAP * 4);       // windowed CSR
    int* staging   = (int*)alloc((size_t)nbuck * CAP * 4);
    _Float16* w1h  = (_Float16*)alloc((size_t)128 * 128 * 2);
    _Float16* w2h  = (_Float16*)alloc((size_t)128 * 128 * 2);
    // zeroed region start:
    char* zbase    = p;
    int* bcur      = (int*)alloc((size_t)MAXBUCK * 4);           // relative counts
    int* gstart    = (int*)alloc((size_t)G * 4);
    int* gend      = (int*)alloc((size_t)G * 4);
    float* pm      = (float*)alloc((size_t)G * 128 * 4);         // pooled max [G,128]
    size_t zbytes  = (size_t)(p - zbase);

    int nchunk = (E + BIN_CHUNK - 1) / BIN_CHUNK;      // 391 (covers N too)

    // one memset replaces k_init; W-convert folded into k_bin blocks 0..63
    hipMemsetAsync(zbase, 0, zbytes, stream);
    k_bin<<<nchunk, 256, 0, stream>>>(src, dst, bcur, staging, batch,
                                      gstart, gend, W1, W2, w1h, w2h,
                                      E, N, nbuck);
    k_bcsr<<<nbuck, BUCKET_SIZE, 0, stream>>>(staging, bcur, esrc, rowstart, deg, N);

    // layer 1
    k_gemm<float><<<(N + 255) / 256, 512, 0, stream>>>(x, w1h, b1, A, N);
    k_agg<<<(N + 3) / 4, 256, 0, stream>>>(A, esrc, rowstart, deg, B, N);
    // layer 2
    k_gemm<_Float16><<<(N + 255) / 256, 512, 0, stream>>>(B, w2h, b2, A2, N);
    // fused agg2 + pool (span-local max, per-span atomicMax flush)
    k_aggp2<<<(N + 63) / 64, 256, 0, stream>>>(A2, esrc, rowstart, deg, batch, pm, N);
    // head
    k_fc<<<G, 128, 0, stream>>>(pm, Wf1, bf1, Wf2, bf2, (float*)d_out);
}